// Round 5
// baseline (632.537 us; speedup 1.0000x reference)
//
#include <hip/hip_runtime.h>
#include <cstdint>
#include <cstddef>

typedef unsigned short ushort_t;
typedef unsigned int uint_t;

__device__ inline ushort_t f2bf(float f) {
  uint_t u = __float_as_uint(f);
  uint_t r = (u + 0x7fffu + ((u >> 16) & 1u)) >> 16;
  return (ushort_t)r;
}
__device__ inline float bfl(uint_t u) { return __uint_as_float(u << 16); }
__device__ inline float bfh(uint_t u) { return __uint_as_float(u & 0xffff0000u); }
__device__ inline float bf1(ushort_t v) { return __uint_as_float(((uint_t)v) << 16); }

// ---------------- CSR construction ----------------

__global__ void deg_kernel(const int* __restrict__ edst, int* __restrict__ deg, int E) {
  int i = blockIdx.x * 256 + threadIdx.x;
  if (i < E) atomicAdd(&deg[edst[i]], 1);
}

__global__ void chunk_sum_kernel(const int* __restrict__ deg, int* __restrict__ csum, int n) {
  __shared__ int wsum[16];
  int t = threadIdx.x;
  int i = blockIdx.x * 1024 + t;
  int v = (i < n) ? deg[i] : 0;
  for (int m = 1; m < 64; m <<= 1) v += __shfl_xor(v, m);
  if ((t & 63) == 0) wsum[t >> 6] = v;
  __syncthreads();
  if (t == 0) {
    int s = 0;
    for (int j = 0; j < 16; ++j) s += wsum[j];
    csum[blockIdx.x] = s;
  }
}

__global__ void scan_chunks_kernel(int* __restrict__ csum, int nchunks) {
  __shared__ int wsum[16];
  int t = threadIdx.x;
  int lane = t & 63, w = t >> 6;
  int x = (t < nchunks) ? csum[t] : 0;
  for (int off = 1; off < 64; off <<= 1) { int y = __shfl_up(x, off); if (lane >= off) x += y; }
  if (lane == 63) wsum[w] = x;
  __syncthreads();
  if (t < 16) {
    int s = wsum[t];
    for (int off = 1; off < 16; off <<= 1) { int y = __shfl_up(s, off); if (t >= off) s += y; }
    wsum[t] = s;
  }
  __syncthreads();
  if (w > 0) x += wsum[w - 1];
  if (t < nchunks) csum[t] = x;
}

__global__ void scan_final_kernel(const int* __restrict__ deg, const int* __restrict__ csum,
                                  int* __restrict__ rowptr, int n) {
  __shared__ int wsum[16];
  int t = threadIdx.x, b = blockIdx.x;
  int i = b * 1024 + t;
  int lane = t & 63, w = t >> 6;
  int x = (i < n) ? deg[i] : 0;
  for (int off = 1; off < 64; off <<= 1) { int y = __shfl_up(x, off); if (lane >= off) x += y; }
  if (lane == 63) wsum[w] = x;
  __syncthreads();
  if (t < 16) {
    int s = wsum[t];
    for (int off = 1; off < 16; off <<= 1) { int y = __shfl_up(s, off); if (t >= off) s += y; }
    wsum[t] = s;
  }
  __syncthreads();
  if (w > 0) x += wsum[w - 1];
  int off0 = (b > 0) ? csum[b - 1] : 0;
  if (i < n) rowptr[i + 1] = off0 + x;
  if (b == 0 && t == 0) rowptr[0] = 0;
}

__global__ void fill_kernel(const int* __restrict__ esrc, const int* __restrict__ edst,
                            const int* __restrict__ rowptr, int* __restrict__ fillc,
                            int* __restrict__ csr_src, int E) {
  int i = blockIdx.x * 256 + threadIdx.x;
  if (i < E) {
    int d = edst[i];
    int pos = atomicAdd(&fillc[d], 1);
    csr_src[rowptr[d] + pos] = esrc[i];
  }
}

// ---------------- GEMM1 + att1 fused: h1b(bf16) = x@W1; a_s/a_d dots (f32) ----------------
__global__ void gemm1_att1_kernel(const float* __restrict__ x, const float* __restrict__ W,
                                  const float* __restrict__ asw, const float* __restrict__ adw,
                                  ushort_t* __restrict__ h1b, float* __restrict__ a_s,
                                  float* __restrict__ a_d, int n) {
  __shared__ float wlds[128 * 128];
  int t = threadIdx.x;
  for (int i = t * 4; i < 128 * 128; i += 256 * 4)
    *(float4*)&wlds[i] = *(const float4*)&W[i];
  __syncthreads();
  int cg = t & 31, rg = t >> 5;
  int c0 = cg * 4;
  int row0 = blockIdx.x * 64 + rg * 8;
  float acc[8][4] = {};
  const float* xr[8];
  #pragma unroll
  for (int i = 0; i < 8; ++i) {
    int r = row0 + i;
    xr[i] = x + (size_t)(r < n ? r : 0) * 128;
  }
  #pragma unroll 4
  for (int k = 0; k < 128; ++k) {
    float4 w4 = *(float4*)&wlds[k * 128 + c0];
    #pragma unroll
    for (int i = 0; i < 8; ++i) {
      float xv = xr[i][k];
      acc[i][0] += xv * w4.x; acc[i][1] += xv * w4.y;
      acc[i][2] += xv * w4.z; acc[i][3] += xv * w4.w;
    }
  }
  float4 as4 = *(const float4*)&asw[c0];
  float4 ad4 = *(const float4*)&adw[c0];
  int hd = cg >> 2;
  bool leader = (cg & 3) == 0;
  #pragma unroll
  for (int i = 0; i < 8; ++i) {
    int r = row0 + i;
    float ps = acc[i][0] * as4.x + acc[i][1] * as4.y + acc[i][2] * as4.z + acc[i][3] * as4.w;
    float pd = acc[i][0] * ad4.x + acc[i][1] * ad4.y + acc[i][2] * ad4.z + acc[i][3] * ad4.w;
    ps += __shfl_xor(ps, 1); ps += __shfl_xor(ps, 2);
    pd += __shfl_xor(pd, 1); pd += __shfl_xor(pd, 2);
    if (r < n) {
      ushort_t hb4[4] = { f2bf(acc[i][0]), f2bf(acc[i][1]), f2bf(acc[i][2]), f2bf(acc[i][3]) };
      *(uint2*)&h1b[(size_t)r * 128 + c0] = *(uint2*)hb4;
      if (leader) {
        a_s[(size_t)r * 8 + hd] = ps;
        a_d[(size_t)r * 8 + hd] = pd;
      }
    }
  }
}

// ---------------- alpha1: normalized attention weights, layer 1 ----------------
// one wave per dst; lane = (edge_slot e = t>>3, head h = t&7).
__global__ void alpha1_kernel(const int* __restrict__ rowptr, const int* __restrict__ csr_src,
                              const float* __restrict__ a_s, const float* __restrict__ a_d,
                              ushort_t* __restrict__ alpha1, int n) {
  int t = threadIdx.x & 63;
  int w = threadIdx.x >> 6;
  int dst = blockIdx.x * 4 + w;
  if (dst >= n) return;
  int beg = rowptr[dst], end = rowptr[dst + 1];
  if (beg == end) return;
  int h = t & 7, el = t >> 3;
  float adv = a_d[(size_t)dst * 8 + h];
  float M = -1e30f, S = 0.f;
  for (int base = beg; base < end; base += 8) {
    int eidx = base + el;
    bool valid = eidx < end;
    int s = csr_src[valid ? eidx : beg];
    float e = a_s[(size_t)s * 8 + h] + adv;
    e = e > 0.f ? e : 0.2f * e;
    e = valid ? e : -1e30f;
    float m = e;
    m = fmaxf(m, __shfl_xor(m, 8));
    m = fmaxf(m, __shfl_xor(m, 16));
    m = fmaxf(m, __shfl_xor(m, 32));
    float nm = fmaxf(M, m);
    float p = valid ? __expf(e - nm) : 0.f;
    float ps = p;
    ps += __shfl_xor(ps, 8);
    ps += __shfl_xor(ps, 16);
    ps += __shfl_xor(ps, 32);
    S = S * __expf(M - nm) + ps;
    M = nm;
  }
  float inv = 1.f / (S + 1e-16f);
  for (int base = beg; base < end; base += 8) {
    int eidx = base + el;
    if (eidx < end) {
      int s = csr_src[eidx];
      float e = a_s[(size_t)s * 8 + h] + adv;
      e = e > 0.f ? e : 0.2f * e;
      alpha1[(size_t)eidx * 8 + h] = f2bf(__expf(e - M) * inv);
    }
  }
}

// ---------------- GAT layer 1 aggregate: pure alpha-weighted gather ----------------
// one wave per dst; lane t owns channels 2t, 2t+1 (head hh = t>>3).
__global__ void gat1_agg_kernel(const int* __restrict__ rowptr, const int* __restrict__ csr_src,
                                const ushort_t* __restrict__ h1b,
                                const ushort_t* __restrict__ alpha1,
                                const float* __restrict__ b1, float* __restrict__ hmid, int n) {
  int t = threadIdx.x & 63;
  int w = threadIdx.x >> 6;
  int dst = blockIdx.x * 4 + w;
  if (dst >= n) return;
  int beg = rowptr[dst], end = rowptr[dst + 1];
  int hh = t >> 3;
  float acc0 = 0.f, acc1 = 0.f;
  for (int base = beg; base < end; base += 64) {
    int cnt = min(64, end - base);
    int s = csr_src[min(base + t, end - 1)];
    #pragma unroll 4
    for (int i = 0; i < cnt; ++i) {
      int si = __shfl(s, i);
      float a = bf1(alpha1[(size_t)(base + i) * 8 + hh]);
      uint_t hv = *(const uint_t*)(h1b + (size_t)si * 128 + 2 * t);
      acc0 = fmaf(a, bfl(hv), acc0);
      acc1 = fmaf(a, bfh(hv), acc1);
    }
  }
  float2 b = *(const float2*)&b1[2 * t];
  float v0 = acc0 + b.x;
  float v1 = acc1 + b.y;
  v0 = v0 > 0.f ? v0 : (__expf(v0) - 1.f);
  v1 = v1 > 0.f ? v1 : (__expf(v1) - 1.f);
  float2 o = { v0, v1 };
  *(float2*)&hmid[(size_t)dst * 128 + 2 * t] = o;
}

// ---------------- GEMM2 + att2 fused: h2b(bf16) = hmid @ W2; a_s2/a_d2 (f32) ----------------
__global__ void gemm2_att2_kernel(const float* __restrict__ hmid, const float* __restrict__ W2,
                                  const float* __restrict__ asw, const float* __restrict__ adw,
                                  ushort_t* __restrict__ h2b, float* __restrict__ a_s2,
                                  float* __restrict__ a_d2, int n) {
  __shared__ float w[128 * 16];
  int t = threadIdx.x;
  for (int i = t; i < 128 * 16; i += 256) w[i] = W2[i];
  __syncthreads();
  int gid = blockIdx.x * 256 + t;
  int node = gid >> 4, c = gid & 15;
  if (node >= n) return;
  const float* row = &hmid[(size_t)node * 128];
  float acc = 0.f;
  #pragma unroll 4
  for (int k = 0; k < 128; ++k) acc += row[k] * w[k * 16 + c];
  h2b[(size_t)node * 16 + c] = f2bf(acc);
  float ps = acc * asw[c], pd = acc * adw[c];
  #pragma unroll
  for (int m = 1; m < 16; m <<= 1) { ps += __shfl_xor(ps, m); pd += __shfl_xor(pd, m); }
  if (c == 0) { a_s2[node] = ps; a_d2[node] = pd; }
}

// ---------------- alpha2: normalized attention weights, layer 2 (1 head) ----------------
// one wave per dst; lane = edge slot.
__global__ void alpha2_kernel(const int* __restrict__ rowptr, const int* __restrict__ csr_src,
                              const float* __restrict__ a_s2, const float* __restrict__ a_d2,
                              float* __restrict__ alpha2, int n) {
  int t = threadIdx.x & 63;
  int w = threadIdx.x >> 6;
  int dst = blockIdx.x * 4 + w;
  if (dst >= n) return;
  int beg = rowptr[dst], end = rowptr[dst + 1];
  if (beg == end) return;
  float adv = a_d2[dst];
  float M = -1e30f, S = 0.f;
  for (int base = beg; base < end; base += 64) {
    int eidx = base + t;
    bool valid = eidx < end;
    int s = csr_src[valid ? eidx : beg];
    float e = a_s2[s] + adv;
    e = e > 0.f ? e : 0.2f * e;
    e = valid ? e : -1e30f;
    float m = e;
    #pragma unroll
    for (int o = 1; o < 64; o <<= 1) m = fmaxf(m, __shfl_xor(m, o));
    float nm = fmaxf(M, m);
    float p = valid ? __expf(e - nm) : 0.f;
    float ps = p;
    #pragma unroll
    for (int o = 1; o < 64; o <<= 1) ps += __shfl_xor(ps, o);
    S = S * __expf(M - nm) + ps;
    M = nm;
  }
  float inv = 1.f / (S + 1e-16f);
  for (int base = beg; base < end; base += 64) {
    int eidx = base + t;
    if (eidx < end) {
      int s = csr_src[eidx];
      float e = a_s2[s] + adv;
      e = e > 0.f ? e : 0.2f * e;
      alpha2[eidx] = __expf(e - M) * inv;
    }
  }
}

// ---------------- GAT layer 2 aggregate + pooled atomics (16-lane group per dst) ----------------
__global__ void gat2_agg_kernel(const int* __restrict__ rowptr, const int* __restrict__ csr_src,
                                const ushort_t* __restrict__ h2b,
                                const float* __restrict__ alpha2, const float* __restrict__ b2,
                                const int* __restrict__ batch,
                                float* __restrict__ pooled, float* __restrict__ cntb,
                                int n, int G) {
  __shared__ float pooledL[17][16];
  __shared__ float cntL[17];
  int t = threadIdx.x;
  if (t < 17) cntL[t] = 0.f;
  for (int i = t; i < 17 * 16; i += 256) ((float*)pooledL)[i] = 0.f;
  __syncthreads();

  int grp = t >> 4, c = t & 15;
  int dst = blockIdx.x * 16 + grp;
  int gfirst = batch[blockIdx.x * 16];

  if (dst < n) {
    int beg = rowptr[dst], end = rowptr[dst + 1];
    float acc = 0.f;
    for (int base = beg; base < end; base += 16) {
      int cnt = min(16, end - base);
      int idx = min(base + c, end - 1);
      int sv = csr_src[idx];
      float av = alpha2[idx];
      #pragma unroll 4
      for (int i = 0; i < cnt; ++i) {
        float ai = __shfl(av, i, 16);
        int   si = __shfl(sv, i, 16);
        acc = fmaf(ai, bf1(h2b[(size_t)si * 16 + c]), acc);
      }
    }
    float v = acc + b2[c];
    int g = batch[dst];
    int gi = g - gfirst;
    if (gi <= 16) {
      atomicAdd(&pooledL[gi][c], v);
      if (c == 0) atomicAdd(&cntL[gi], 1.f);
    } else {
      atomicAdd(&pooled[g * 16 + c], v);
      if (c == 0) atomicAdd(&cntb[g], 1.f);
    }
  }
  __syncthreads();

  int w = t >> 5, lane32 = t & 31;
  for (int gi = w; gi < 17; gi += 8) {
    if (cntL[gi] > 0.f) {
      int g = gfirst + gi;
      if (lane32 < 16) atomicAdd(&pooled[g * 16 + lane32], pooledL[gi][lane32]);
      else if (lane32 == 16) atomicAdd(&cntb[g], cntL[gi]);
    }
  }
}

// ---------------- final: mean + log_softmax ----------------
__global__ void final_kernel(const float* __restrict__ pooled, const float* __restrict__ cntb,
                             float* __restrict__ out, int G) {
  int g = threadIdx.x;
  if (g >= G) return;
  float c = fmaxf(cntb[g], 1.f);
  float v[16];
  float m = -1e30f;
  #pragma unroll
  for (int i = 0; i < 16; ++i) { v[i] = pooled[g * 16 + i] / c; m = fmaxf(m, v[i]); }
  float s = 0.f;
  #pragma unroll
  for (int i = 0; i < 16; ++i) s += __expf(v[i] - m);
  float ls = logf(s);
  #pragma unroll
  for (int i = 0; i < 16; ++i) out[g * 16 + i] = v[i] - m - ls;
}

// ---------------- launcher ----------------
extern "C" void kernel_launch(void* const* d_in, const int* in_sizes, int n_in,
                              void* d_out, int out_size, void* d_ws, size_t ws_size,
                              hipStream_t stream) {
  const float* x    = (const float*)d_in[0];
  const int*   eidx = (const int*)  d_in[1];
  const int*   batch= (const int*)  d_in[2];
  const float* W1   = (const float*)d_in[3];
  const float* as1w = (const float*)d_in[4];
  const float* ad1w = (const float*)d_in[5];
  const float* b1   = (const float*)d_in[6];
  const float* W2   = (const float*)d_in[7];
  const float* as2w = (const float*)d_in[8];
  const float* ad2w = (const float*)d_in[9];
  const float* b2   = (const float*)d_in[10];
  float* out = (float*)d_out;

  int N = in_sizes[0] / 128;
  int E = in_sizes[1] / 2;
  int G = out_size / 16;
  const int* esrc = eidx;
  const int* edst = eidx + E;

  char* p = (char*)d_ws;
  auto alloc = [&](size_t bytes) {
    char* r = p;
    p += (bytes + 255) & ~(size_t)255;
    return r;
  };
  ushort_t* h1b = (ushort_t*)alloc((size_t)N * 128 * 2);
  float* hmid = (float*)alloc((size_t)N * 128 * 4);
  ushort_t* h2b = (ushort_t*)alloc((size_t)N * 16 * 2);
  float* as1  = (float*)alloc((size_t)N * 8 * 4);
  float* ad1  = (float*)alloc((size_t)N * 8 * 4);
  float* as2  = (float*)alloc((size_t)N * 4);
  float* ad2  = (float*)alloc((size_t)N * 4);
  ushort_t* alpha1 = (ushort_t*)alloc((size_t)E * 8 * 2);
  float* alpha2 = (float*)alloc((size_t)E * 4);
  float* pooled = (float*)alloc((size_t)(G * 16 + G) * 4);
  float* cntb = pooled + G * 16;
  int* deg    = (int*)alloc((size_t)N * 4);
  int* rowptr = (int*)alloc((size_t)(N + 1) * 4);
  int* fillc  = (int*)alloc((size_t)N * 4);
  int* csr    = (int*)alloc((size_t)E * 4);
  int* csum   = (int*)alloc(1024 * 4);

  hipMemsetAsync(deg, 0, (size_t)N * 4, stream);
  hipMemsetAsync(fillc, 0, (size_t)N * 4, stream);
  hipMemsetAsync(pooled, 0, (size_t)(G * 16 + G) * 4, stream);

  int nchunks = (N + 1023) / 1024;
  deg_kernel<<<(E + 255) / 256, 256, 0, stream>>>(edst, deg, E);
  chunk_sum_kernel<<<nchunks, 1024, 0, stream>>>(deg, csum, N);
  scan_chunks_kernel<<<1, 1024, 0, stream>>>(csum, nchunks);
  scan_final_kernel<<<nchunks, 1024, 0, stream>>>(deg, csum, rowptr, N);
  fill_kernel<<<(E + 255) / 256, 256, 0, stream>>>(esrc, edst, rowptr, fillc, csr, E);

  gemm1_att1_kernel<<<(N + 63) / 64, 256, 0, stream>>>(x, W1, as1w, ad1w, h1b, as1, ad1, N);
  alpha1_kernel<<<(N + 3) / 4, 256, 0, stream>>>(rowptr, csr, as1, ad1, alpha1, N);
  gat1_agg_kernel<<<(N + 3) / 4, 256, 0, stream>>>(rowptr, csr, h1b, alpha1, b1, hmid, N);
  gemm2_att2_kernel<<<(N * 16 + 255) / 256, 256, 0, stream>>>(hmid, W2, as2w, ad2w, h2b, as2, ad2, N);
  alpha2_kernel<<<(N + 3) / 4, 256, 0, stream>>>(rowptr, csr, as2, ad2, alpha2, N);
  gat2_agg_kernel<<<(N + 15) / 16, 256, 0, stream>>>(rowptr, csr, h2b, alpha2, b2, batch, pooled, cntb, N, G);
  final_kernel<<<1, (G + 63) / 64 * 64, 0, stream>>>(pooled, cntb, out, G);
}

// Round 6
// 552.971 us; speedup vs baseline: 1.1439x; 1.1439x over previous
//
#include <hip/hip_runtime.h>
#include <cstdint>
#include <cstddef>

typedef unsigned short ushort_t;
typedef unsigned int uint_t;

#define NBMAX 1024   // max buckets (N <= 131072)
#define EPB   16384  // edges per block in hist/scatter passes

__device__ inline ushort_t f2bf(float f) {
  uint_t u = __float_as_uint(f);
  uint_t r = (u + 0x7fffu + ((u >> 16) & 1u)) >> 16;
  return (ushort_t)r;
}
__device__ inline float bfl(uint_t u) { return __uint_as_float(u << 16); }
__device__ inline float bfh(uint_t u) { return __uint_as_float(u & 0xffff0000u); }
__device__ inline float bf1(ushort_t v) { return __uint_as_float(((uint_t)v) << 16); }

// ---------------- CSR construction: bucketed counting sort ----------------

// Pass A: per-block bucket histogram; reserve contiguous range per (block,bucket).
__global__ void bucket_hist_kernel(const int* __restrict__ edst, int* __restrict__ gcount,
                                   int* __restrict__ myBase, int E, int NB) {
  __shared__ int hist[NBMAX];
  int t = threadIdx.x;
  int blk = blockIdx.x;
  for (int i = t; i < NB; i += 256) hist[i] = 0;
  __syncthreads();
  int b0 = blk * EPB, e1 = min(b0 + EPB, E);
  for (int i = b0 + t; i < e1; i += 256) atomicAdd(&hist[edst[i] >> 7], 1);
  __syncthreads();
  for (int i = t; i < NB; i += 256) {
    int c = hist[i];
    myBase[(size_t)blk * NB + i] = c ? atomicAdd(&gcount[i], c) : 0;
  }
}

// Pass B': exclusive scan of bucket counts -> boff[NB+1].
__global__ void bucket_scan_kernel(const int* __restrict__ gcount, int* __restrict__ boff, int NB) {
  __shared__ int ws[16];
  int t = threadIdx.x;
  int lane = t & 63, w = t >> 6;
  int v = (t < NB) ? gcount[t] : 0;
  for (int o = 1; o < 64; o <<= 1) { int y = __shfl_up(v, o); if (lane >= o) v += y; }
  if (lane == 63) ws[w] = v;
  __syncthreads();
  if (t < 16) {
    int s = ws[t];
    for (int o = 1; o < 16; o <<= 1) { int y = __shfl_up(s, o); if (t >= o) s += y; }
    ws[t] = s;
  }
  __syncthreads();
  if (w > 0) v += ws[w - 1];
  if (t < NB) boff[t + 1] = v;
  if (t == 0) boff[0] = 0;
}

// Pass B: scatter (dst,src) pairs into bucket-grouped array via reserved ranges.
__global__ void bucket_scatter_kernel(const int* __restrict__ esrc, const int* __restrict__ edst,
                                      const int* __restrict__ boff, const int* __restrict__ myBase,
                                      int2* __restrict__ pairs, int E, int NB) {
  __shared__ int cursor[NBMAX];
  int t = threadIdx.x;
  int blk = blockIdx.x;
  for (int i = t; i < NB; i += 256) cursor[i] = boff[i] + myBase[(size_t)blk * NB + i];
  __syncthreads();
  int b0 = blk * EPB, e1 = min(b0 + EPB, E);
  for (int i = b0 + t; i < e1; i += 256) {
    int d = edst[i], s = esrc[i];
    int pos = atomicAdd(&cursor[d >> 7], 1);
    int2 pr; pr.x = d; pr.y = s;
    pairs[pos] = pr;
  }
}

// Pass C: one block per bucket (128 dsts). Build rowptr + dst-sorted csr in the
// bucket's private window (single owner -> lines written once).
__global__ void bucket_csr_kernel(const int2* __restrict__ pairs, const int* __restrict__ boff,
                                  int* __restrict__ rowptr, int* __restrict__ csr, int n, int NB) {
  __shared__ int cnt[128];
  __shared__ int ws2[2];
  int b = blockIdx.x;
  int t = threadIdx.x;   // 128 threads
  int lo = boff[b], hi = boff[b + 1];
  int D0 = b << 7;
  cnt[t] = 0;
  __syncthreads();
  for (int i = lo + t; i < hi; i += 128) atomicAdd(&cnt[pairs[i].x - D0], 1);
  __syncthreads();
  int lane = t & 63, w = t >> 6;
  int v = cnt[t];
  int vx = v;
  for (int o = 1; o < 64; o <<= 1) { int y = __shfl_up(vx, o); if (lane >= o) vx += y; }
  if (lane == 63) ws2[w] = vx;
  __syncthreads();
  int incl = vx + (w ? ws2[0] : 0);
  int excl = incl - v;
  int d = D0 + t;
  if (d <= n) rowptr[d] = lo + excl;
  __syncthreads();
  cnt[t] = excl;
  __syncthreads();
  for (int i = lo + t; i < hi; i += 128) {
    int2 pr = pairs[i];
    int pos = atomicAdd(&cnt[pr.x - D0], 1);
    csr[lo + pos] = pr.y;
  }
}

// ---------------- GEMM1 + att1 fused: h1b(bf16) = x@W1; a_s/a_d dots (f32) ----------------
__global__ void gemm1_att1_kernel(const float* __restrict__ x, const float* __restrict__ W,
                                  const float* __restrict__ asw, const float* __restrict__ adw,
                                  ushort_t* __restrict__ h1b, float* __restrict__ a_s,
                                  float* __restrict__ a_d, int n) {
  __shared__ float wlds[128 * 128];
  int t = threadIdx.x;
  for (int i = t * 4; i < 128 * 128; i += 256 * 4)
    *(float4*)&wlds[i] = *(const float4*)&W[i];
  __syncthreads();
  int cg = t & 31, rg = t >> 5;
  int c0 = cg * 4;
  int row0 = blockIdx.x * 64 + rg * 8;
  float acc[8][4] = {};
  const float* xr[8];
  #pragma unroll
  for (int i = 0; i < 8; ++i) {
    int r = row0 + i;
    xr[i] = x + (size_t)(r < n ? r : 0) * 128;
  }
  #pragma unroll 4
  for (int k = 0; k < 128; ++k) {
    float4 w4 = *(float4*)&wlds[k * 128 + c0];
    #pragma unroll
    for (int i = 0; i < 8; ++i) {
      float xv = xr[i][k];
      acc[i][0] += xv * w4.x; acc[i][1] += xv * w4.y;
      acc[i][2] += xv * w4.z; acc[i][3] += xv * w4.w;
    }
  }
  float4 as4 = *(const float4*)&asw[c0];
  float4 ad4 = *(const float4*)&adw[c0];
  int hd = cg >> 2;
  bool leader = (cg & 3) == 0;
  #pragma unroll
  for (int i = 0; i < 8; ++i) {
    int r = row0 + i;
    float ps = acc[i][0] * as4.x + acc[i][1] * as4.y + acc[i][2] * as4.z + acc[i][3] * as4.w;
    float pd = acc[i][0] * ad4.x + acc[i][1] * ad4.y + acc[i][2] * ad4.z + acc[i][3] * ad4.w;
    ps += __shfl_xor(ps, 1); ps += __shfl_xor(ps, 2);
    pd += __shfl_xor(pd, 1); pd += __shfl_xor(pd, 2);
    if (r < n) {
      ushort_t hb4[4] = { f2bf(acc[i][0]), f2bf(acc[i][1]), f2bf(acc[i][2]), f2bf(acc[i][3]) };
      *(uint2*)&h1b[(size_t)r * 128 + c0] = *(uint2*)hb4;
      if (leader) {
        a_s[(size_t)r * 8 + hd] = ps;
        a_d[(size_t)r * 8 + hd] = pd;
      }
    }
  }
}

// ---------------- alpha1: normalized attention weights, layer 1 ----------------
__global__ void alpha1_kernel(const int* __restrict__ rowptr, const int* __restrict__ csr_src,
                              const float* __restrict__ a_s, const float* __restrict__ a_d,
                              ushort_t* __restrict__ alpha1, int n) {
  int t = threadIdx.x & 63;
  int w = threadIdx.x >> 6;
  int dst = blockIdx.x * 4 + w;
  if (dst >= n) return;
  int beg = rowptr[dst], end = rowptr[dst + 1];
  if (beg == end) return;
  int h = t & 7, el = t >> 3;
  float adv = a_d[(size_t)dst * 8 + h];
  float M = -1e30f, S = 0.f;
  for (int base = beg; base < end; base += 8) {
    int eidx = base + el;
    bool valid = eidx < end;
    int s = csr_src[valid ? eidx : beg];
    float e = a_s[(size_t)s * 8 + h] + adv;
    e = e > 0.f ? e : 0.2f * e;
    e = valid ? e : -1e30f;
    float m = e;
    m = fmaxf(m, __shfl_xor(m, 8));
    m = fmaxf(m, __shfl_xor(m, 16));
    m = fmaxf(m, __shfl_xor(m, 32));
    float nm = fmaxf(M, m);
    float p = valid ? __expf(e - nm) : 0.f;
    float ps = p;
    ps += __shfl_xor(ps, 8);
    ps += __shfl_xor(ps, 16);
    ps += __shfl_xor(ps, 32);
    S = S * __expf(M - nm) + ps;
    M = nm;
  }
  float inv = 1.f / (S + 1e-16f);
  for (int base = beg; base < end; base += 8) {
    int eidx = base + el;
    if (eidx < end) {
      int s = csr_src[eidx];
      float e = a_s[(size_t)s * 8 + h] + adv;
      e = e > 0.f ? e : 0.2f * e;
      alpha1[(size_t)eidx * 8 + h] = f2bf(__expf(e - M) * inv);
    }
  }
}

// ---------------- GAT layer 1 aggregate: pure alpha-weighted gather ----------------
__global__ void gat1_agg_kernel(const int* __restrict__ rowptr, const int* __restrict__ csr_src,
                                const ushort_t* __restrict__ h1b,
                                const ushort_t* __restrict__ alpha1,
                                const float* __restrict__ b1, float* __restrict__ hmid, int n) {
  int t = threadIdx.x & 63;
  int w = threadIdx.x >> 6;
  int dst = blockIdx.x * 4 + w;
  if (dst >= n) return;
  int beg = rowptr[dst], end = rowptr[dst + 1];
  int hh = t >> 3;
  float acc0 = 0.f, acc1 = 0.f;
  for (int base = beg; base < end; base += 64) {
    int cnt = min(64, end - base);
    int s = csr_src[min(base + t, end - 1)];
    #pragma unroll 4
    for (int i = 0; i < cnt; ++i) {
      int si = __shfl(s, i);
      float a = bf1(alpha1[(size_t)(base + i) * 8 + hh]);
      uint_t hv = *(const uint_t*)(h1b + (size_t)si * 128 + 2 * t);
      acc0 = fmaf(a, bfl(hv), acc0);
      acc1 = fmaf(a, bfh(hv), acc1);
    }
  }
  float2 b = *(const float2*)&b1[2 * t];
  float v0 = acc0 + b.x;
  float v1 = acc1 + b.y;
  v0 = v0 > 0.f ? v0 : (__expf(v0) - 1.f);
  v1 = v1 > 0.f ? v1 : (__expf(v1) - 1.f);
  float2 o = { v0, v1 };
  *(float2*)&hmid[(size_t)dst * 128 + 2 * t] = o;
}

// ---------------- GEMM2 + att2 fused: h2b(bf16) = hmid @ W2; a_s2/a_d2 (f32) ----------------
__global__ void gemm2_att2_kernel(const float* __restrict__ hmid, const float* __restrict__ W2,
                                  const float* __restrict__ asw, const float* __restrict__ adw,
                                  ushort_t* __restrict__ h2b, float* __restrict__ a_s2,
                                  float* __restrict__ a_d2, int n) {
  __shared__ float w[128 * 16];
  int t = threadIdx.x;
  for (int i = t; i < 128 * 16; i += 256) w[i] = W2[i];
  __syncthreads();
  int gid = blockIdx.x * 256 + t;
  int node = gid >> 4, c = gid & 15;
  if (node >= n) return;
  const float* row = &hmid[(size_t)node * 128];
  float acc = 0.f;
  #pragma unroll 4
  for (int k = 0; k < 128; ++k) acc += row[k] * w[k * 16 + c];
  h2b[(size_t)node * 16 + c] = f2bf(acc);
  float ps = acc * asw[c], pd = acc * adw[c];
  #pragma unroll
  for (int m = 1; m < 16; m <<= 1) { ps += __shfl_xor(ps, m); pd += __shfl_xor(pd, m); }
  if (c == 0) { a_s2[node] = ps; a_d2[node] = pd; }
}

// ---------------- alpha2: normalized attention weights, layer 2 (1 head) ----------------
__global__ void alpha2_kernel(const int* __restrict__ rowptr, const int* __restrict__ csr_src,
                              const float* __restrict__ a_s2, const float* __restrict__ a_d2,
                              float* __restrict__ alpha2, int n) {
  int t = threadIdx.x & 63;
  int w = threadIdx.x >> 6;
  int dst = blockIdx.x * 4 + w;
  if (dst >= n) return;
  int beg = rowptr[dst], end = rowptr[dst + 1];
  if (beg == end) return;
  float adv = a_d2[dst];
  float M = -1e30f, S = 0.f;
  for (int base = beg; base < end; base += 64) {
    int eidx = base + t;
    bool valid = eidx < end;
    int s = csr_src[valid ? eidx : beg];
    float e = a_s2[s] + adv;
    e = e > 0.f ? e : 0.2f * e;
    e = valid ? e : -1e30f;
    float m = e;
    #pragma unroll
    for (int o = 1; o < 64; o <<= 1) m = fmaxf(m, __shfl_xor(m, o));
    float nm = fmaxf(M, m);
    float p = valid ? __expf(e - nm) : 0.f;
    float ps = p;
    #pragma unroll
    for (int o = 1; o < 64; o <<= 1) ps += __shfl_xor(ps, o);
    S = S * __expf(M - nm) + ps;
    M = nm;
  }
  float inv = 1.f / (S + 1e-16f);
  for (int base = beg; base < end; base += 64) {
    int eidx = base + t;
    if (eidx < end) {
      int s = csr_src[eidx];
      float e = a_s2[s] + adv;
      e = e > 0.f ? e : 0.2f * e;
      alpha2[eidx] = __expf(e - M) * inv;
    }
  }
}

// ---------------- GAT layer 2 aggregate + pooled atomics (16-lane group per dst) ----------------
__global__ void gat2_agg_kernel(const int* __restrict__ rowptr, const int* __restrict__ csr_src,
                                const ushort_t* __restrict__ h2b,
                                const float* __restrict__ alpha2, const float* __restrict__ b2,
                                const int* __restrict__ batch,
                                float* __restrict__ pooled, float* __restrict__ cntb,
                                int n, int G) {
  __shared__ float pooledL[17][16];
  __shared__ float cntL[17];
  int t = threadIdx.x;
  if (t < 17) cntL[t] = 0.f;
  for (int i = t; i < 17 * 16; i += 256) ((float*)pooledL)[i] = 0.f;
  __syncthreads();

  int grp = t >> 4, c = t & 15;
  int dst = blockIdx.x * 16 + grp;
  int gfirst = batch[blockIdx.x * 16];

  if (dst < n) {
    int beg = rowptr[dst], end = rowptr[dst + 1];
    float acc = 0.f;
    for (int base = beg; base < end; base += 16) {
      int cnt = min(16, end - base);
      int idx = min(base + c, end - 1);
      int sv = csr_src[idx];
      float av = alpha2[idx];
      #pragma unroll 4
      for (int i = 0; i < cnt; ++i) {
        float ai = __shfl(av, i, 16);
        int   si = __shfl(sv, i, 16);
        acc = fmaf(ai, bf1(h2b[(size_t)si * 16 + c]), acc);
      }
    }
    float v = acc + b2[c];
    int g = batch[dst];
    int gi = g - gfirst;
    if (gi <= 16) {
      atomicAdd(&pooledL[gi][c], v);
      if (c == 0) atomicAdd(&cntL[gi], 1.f);
    } else {
      atomicAdd(&pooled[g * 16 + c], v);
      if (c == 0) atomicAdd(&cntb[g], 1.f);
    }
  }
  __syncthreads();

  int w = t >> 5, lane32 = t & 31;
  for (int gi = w; gi < 17; gi += 8) {
    if (cntL[gi] > 0.f) {
      int g = gfirst + gi;
      if (lane32 < 16) atomicAdd(&pooled[g * 16 + lane32], pooledL[gi][lane32]);
      else if (lane32 == 16) atomicAdd(&cntb[g], cntL[gi]);
    }
  }
}

// ---------------- final: mean + log_softmax ----------------
__global__ void final_kernel(const float* __restrict__ pooled, const float* __restrict__ cntb,
                             float* __restrict__ out, int G) {
  int g = threadIdx.x;
  if (g >= G) return;
  float c = fmaxf(cntb[g], 1.f);
  float v[16];
  float m = -1e30f;
  #pragma unroll
  for (int i = 0; i < 16; ++i) { v[i] = pooled[g * 16 + i] / c; m = fmaxf(m, v[i]); }
  float s = 0.f;
  #pragma unroll
  for (int i = 0; i < 16; ++i) s += __expf(v[i] - m);
  float ls = logf(s);
  #pragma unroll
  for (int i = 0; i < 16; ++i) out[g * 16 + i] = v[i] - m - ls;
}

// ---------------- launcher ----------------
extern "C" void kernel_launch(void* const* d_in, const int* in_sizes, int n_in,
                              void* d_out, int out_size, void* d_ws, size_t ws_size,
                              hipStream_t stream) {
  const float* x    = (const float*)d_in[0];
  const int*   eidx = (const int*)  d_in[1];
  const int*   batch= (const int*)  d_in[2];
  const float* W1   = (const float*)d_in[3];
  const float* as1w = (const float*)d_in[4];
  const float* ad1w = (const float*)d_in[5];
  const float* b1   = (const float*)d_in[6];
  const float* W2   = (const float*)d_in[7];
  const float* as2w = (const float*)d_in[8];
  const float* ad2w = (const float*)d_in[9];
  const float* b2   = (const float*)d_in[10];
  float* out = (float*)d_out;

  int N = in_sizes[0] / 128;
  int E = in_sizes[1] / 2;
  int G = out_size / 16;
  const int* esrc = eidx;
  const int* edst = eidx + E;

  int NB = (N + 127) >> 7;              // buckets of 128 dsts (<= NBMAX)
  int nblkA = (E + EPB - 1) / EPB;

  char* p = (char*)d_ws;
  auto alloc = [&](size_t bytes) {
    char* r = p;
    p += (bytes + 255) & ~(size_t)255;
    return r;
  };
  ushort_t* h1b = (ushort_t*)alloc((size_t)N * 128 * 2);
  float* hmid = (float*)alloc((size_t)N * 128 * 4);
  ushort_t* h2b = (ushort_t*)alloc((size_t)N * 16 * 2);
  float* as1  = (float*)alloc((size_t)N * 8 * 4);
  float* ad1  = (float*)alloc((size_t)N * 8 * 4);
  float* as2  = (float*)alloc((size_t)N * 4);
  float* ad2  = (float*)alloc((size_t)N * 4);
  // union: pairs (E*8 B) is dead before alpha1/alpha2 are produced
  size_t a1sz = (size_t)E * 8 * 2, a2sz = (size_t)E * 4;
  size_t unionSz = a1sz + a2sz;                     // >= E*8
  char* U = alloc(unionSz);
  int2* pairs = (int2*)U;
  ushort_t* alpha1 = (ushort_t*)U;
  float* alpha2 = (float*)(U + a1sz);
  float* pooled = (float*)alloc((size_t)(G * 16 + G) * 4);
  float* cntb = pooled + G * 16;
  int* rowptr = (int*)alloc((size_t)(N + 1) * 4);
  int* csr    = (int*)alloc((size_t)E * 4);
  int* gcount = (int*)alloc((size_t)(NBMAX + 1) * 4);
  int* boff   = (int*)alloc((size_t)(NBMAX + 1) * 4);
  int* myBase = (int*)alloc((size_t)nblkA * NB * 4);

  hipMemsetAsync(gcount, 0, (size_t)(NBMAX + 1) * 4, stream);
  hipMemsetAsync(pooled, 0, (size_t)(G * 16 + G) * 4, stream);

  bucket_hist_kernel<<<nblkA, 256, 0, stream>>>(edst, gcount, myBase, E, NB);
  bucket_scan_kernel<<<1, 1024, 0, stream>>>(gcount, boff, NB);
  bucket_scatter_kernel<<<nblkA, 256, 0, stream>>>(esrc, edst, boff, myBase, pairs, E, NB);
  bucket_csr_kernel<<<NB, 128, 0, stream>>>(pairs, boff, rowptr, csr, N, NB);

  gemm1_att1_kernel<<<(N + 63) / 64, 256, 0, stream>>>(x, W1, as1w, ad1w, h1b, as1, ad1, N);
  alpha1_kernel<<<(N + 3) / 4, 256, 0, stream>>>(rowptr, csr, as1, ad1, alpha1, N);
  gat1_agg_kernel<<<(N + 3) / 4, 256, 0, stream>>>(rowptr, csr, h1b, alpha1, b1, hmid, N);
  gemm2_att2_kernel<<<(N * 16 + 255) / 256, 256, 0, stream>>>(hmid, W2, as2w, ad2w, h2b, as2, ad2, N);
  alpha2_kernel<<<(N + 3) / 4, 256, 0, stream>>>(rowptr, csr, as2, ad2, alpha2, N);
  gat2_agg_kernel<<<(N + 15) / 16, 256, 0, stream>>>(rowptr, csr, h2b, alpha2, b2, batch, pooled, cntb, N, G);
  final_kernel<<<1, (G + 63) / 64 * 64, 0, stream>>>(pooled, cntb, out, G);
}

// Round 7
// 481.565 us; speedup vs baseline: 1.3135x; 1.1483x over previous
//
#include <hip/hip_runtime.h>
#include <cstdint>
#include <cstddef>

typedef unsigned short ushort_t;
typedef unsigned int uint_t;

#define NBMAX 1024   // max buckets (N <= 131072)
#define EPB   16384  // edges per block in hist/scatter passes

__device__ inline ushort_t f2bf(float f) {
  uint_t u = __float_as_uint(f);
  uint_t r = (u + 0x7fffu + ((u >> 16) & 1u)) >> 16;
  return (ushort_t)r;
}
__device__ inline float bfl(uint_t u) { return __uint_as_float(u << 16); }
__device__ inline float bfh(uint_t u) { return __uint_as_float(u & 0xffff0000u); }
__device__ inline float bf1(ushort_t v) { return __uint_as_float(((uint_t)v) << 16); }

// ---------------- CSR construction: bucketed counting sort ----------------

__global__ void bucket_hist_kernel(const int* __restrict__ edst, int* __restrict__ gcount,
                                   int* __restrict__ myBase, int E, int NB) {
  __shared__ int hist[NBMAX];
  int t = threadIdx.x;
  int blk = blockIdx.x;
  for (int i = t; i < NB; i += 256) hist[i] = 0;
  __syncthreads();
  int b0 = blk * EPB, e1 = min(b0 + EPB, E);
  for (int i = b0 + t; i < e1; i += 256) atomicAdd(&hist[edst[i] >> 7], 1);
  __syncthreads();
  for (int i = t; i < NB; i += 256) {
    int c = hist[i];
    myBase[(size_t)blk * NB + i] = c ? atomicAdd(&gcount[i], c) : 0;
  }
}

__global__ void bucket_scan_kernel(const int* __restrict__ gcount, int* __restrict__ boff, int NB) {
  __shared__ int ws[16];
  int t = threadIdx.x;
  int lane = t & 63, w = t >> 6;
  int v = (t < NB) ? gcount[t] : 0;
  for (int o = 1; o < 64; o <<= 1) { int y = __shfl_up(v, o); if (lane >= o) v += y; }
  if (lane == 63) ws[w] = v;
  __syncthreads();
  if (t < 16) {
    int s = ws[t];
    for (int o = 1; o < 16; o <<= 1) { int y = __shfl_up(s, o); if (t >= o) s += y; }
    ws[t] = s;
  }
  __syncthreads();
  if (w > 0) v += ws[w - 1];
  if (t < NB) boff[t + 1] = v;
  if (t == 0) boff[0] = 0;
}

// packed pair: (dst & 127) << 25 | src   (requires src < 2^25)
__global__ void bucket_scatter_kernel(const int* __restrict__ esrc, const int* __restrict__ edst,
                                      const int* __restrict__ boff, const int* __restrict__ myBase,
                                      uint_t* __restrict__ pairs, int E, int NB) {
  __shared__ int cursor[NBMAX];
  int t = threadIdx.x;
  int blk = blockIdx.x;
  for (int i = t; i < NB; i += 256) cursor[i] = boff[i] + myBase[(size_t)blk * NB + i];
  __syncthreads();
  int b0 = blk * EPB, e1 = min(b0 + EPB, E);
  for (int i = b0 + t; i < e1; i += 256) {
    int d = edst[i], s = esrc[i];
    int pos = atomicAdd(&cursor[d >> 7], 1);
    pairs[pos] = ((uint_t)(d & 127) << 25) | (uint_t)s;
  }
}

__global__ void bucket_csr_kernel(const uint_t* __restrict__ pairs, const int* __restrict__ boff,
                                  int* __restrict__ rowptr, int* __restrict__ csr, int n, int NB) {
  __shared__ int cnt[128];
  __shared__ int ws2[2];
  int b = blockIdx.x;
  int t = threadIdx.x;   // 128 threads
  int lo = boff[b], hi = boff[b + 1];
  int D0 = b << 7;
  cnt[t] = 0;
  __syncthreads();
  for (int i = lo + t; i < hi; i += 128) atomicAdd(&cnt[pairs[i] >> 25], 1);
  __syncthreads();
  int lane = t & 63, w = t >> 6;
  int v = cnt[t];
  int vx = v;
  for (int o = 1; o < 64; o <<= 1) { int y = __shfl_up(vx, o); if (lane >= o) vx += y; }
  if (lane == 63) ws2[w] = vx;
  __syncthreads();
  int incl = vx + (w ? ws2[0] : 0);
  int excl = incl - v;
  int d = D0 + t;
  if (d <= n) rowptr[d] = lo + excl;
  __syncthreads();
  cnt[t] = excl;
  __syncthreads();
  for (int i = lo + t; i < hi; i += 128) {
    uint_t pr = pairs[i];
    int pos = atomicAdd(&cnt[pr >> 25], 1);
    csr[lo + pos] = (int)(pr & 0x1FFFFFFu);
  }
}

// ---------------- GEMM1 + att1 fused: h1b(bf16) = x@W1; a_s/a_d dots (f32) ----------------
__global__ void gemm1_att1_kernel(const float* __restrict__ x, const float* __restrict__ W,
                                  const float* __restrict__ asw, const float* __restrict__ adw,
                                  ushort_t* __restrict__ h1b, float* __restrict__ a_s,
                                  float* __restrict__ a_d, int n) {
  __shared__ float wlds[128 * 128];
  int t = threadIdx.x;
  for (int i = t * 4; i < 128 * 128; i += 256 * 4)
    *(float4*)&wlds[i] = *(const float4*)&W[i];
  __syncthreads();
  int cg = t & 31, rg = t >> 5;
  int c0 = cg * 4;
  int row0 = blockIdx.x * 64 + rg * 8;
  float acc[8][4] = {};
  const float* xr[8];
  #pragma unroll
  for (int i = 0; i < 8; ++i) {
    int r = row0 + i;
    xr[i] = x + (size_t)(r < n ? r : 0) * 128;
  }
  #pragma unroll 4
  for (int k = 0; k < 128; ++k) {
    float4 w4 = *(float4*)&wlds[k * 128 + c0];
    #pragma unroll
    for (int i = 0; i < 8; ++i) {
      float xv = xr[i][k];
      acc[i][0] += xv * w4.x; acc[i][1] += xv * w4.y;
      acc[i][2] += xv * w4.z; acc[i][3] += xv * w4.w;
    }
  }
  float4 as4 = *(const float4*)&asw[c0];
  float4 ad4 = *(const float4*)&adw[c0];
  int hd = cg >> 2;
  bool leader = (cg & 3) == 0;
  #pragma unroll
  for (int i = 0; i < 8; ++i) {
    int r = row0 + i;
    float ps = acc[i][0] * as4.x + acc[i][1] * as4.y + acc[i][2] * as4.z + acc[i][3] * as4.w;
    float pd = acc[i][0] * ad4.x + acc[i][1] * ad4.y + acc[i][2] * ad4.z + acc[i][3] * ad4.w;
    ps += __shfl_xor(ps, 1); ps += __shfl_xor(ps, 2);
    pd += __shfl_xor(pd, 1); pd += __shfl_xor(pd, 2);
    if (r < n) {
      ushort_t hb4[4] = { f2bf(acc[i][0]), f2bf(acc[i][1]), f2bf(acc[i][2]), f2bf(acc[i][3]) };
      *(uint2*)&h1b[(size_t)r * 128 + c0] = *(uint2*)hb4;
      if (leader) {
        a_s[(size_t)r * 8 + hd] = ps;
        a_d[(size_t)r * 8 + hd] = pd;
      }
    }
  }
}

// ---------------- alpha1: normalized attention weights, layer 1 ----------------
__global__ void alpha1_kernel(const int* __restrict__ rowptr, const int* __restrict__ csr_src,
                              const float* __restrict__ a_s, const float* __restrict__ a_d,
                              ushort_t* __restrict__ alpha1, int n) {
  int t = threadIdx.x & 63;
  int w = threadIdx.x >> 6;
  int dst = blockIdx.x * 4 + w;
  if (dst >= n) return;
  int beg = rowptr[dst], end = rowptr[dst + 1];
  if (beg == end) return;
  int h = t & 7, el = t >> 3;
  float adv = a_d[(size_t)dst * 8 + h];
  float M = -1e30f, S = 0.f;
  for (int base = beg; base < end; base += 8) {
    int eidx = base + el;
    bool valid = eidx < end;
    int s = csr_src[valid ? eidx : beg];
    float e = a_s[(size_t)s * 8 + h] + adv;
    e = e > 0.f ? e : 0.2f * e;
    e = valid ? e : -1e30f;
    float m = e;
    m = fmaxf(m, __shfl_xor(m, 8));
    m = fmaxf(m, __shfl_xor(m, 16));
    m = fmaxf(m, __shfl_xor(m, 32));
    float nm = fmaxf(M, m);
    float p = valid ? __expf(e - nm) : 0.f;
    float ps = p;
    ps += __shfl_xor(ps, 8);
    ps += __shfl_xor(ps, 16);
    ps += __shfl_xor(ps, 32);
    S = S * __expf(M - nm) + ps;
    M = nm;
  }
  float inv = 1.f / (S + 1e-16f);
  for (int base = beg; base < end; base += 8) {
    int eidx = base + el;
    if (eidx < end) {
      int s = csr_src[eidx];
      float e = a_s[(size_t)s * 8 + h] + adv;
      e = e > 0.f ? e : 0.2f * e;
      alpha1[(size_t)eidx * 8 + h] = f2bf(__expf(e - M) * inv);
    }
  }
}

// ---------------- GAT layer 1 aggregate: 4 edges/wave, 16 lanes/edge ----------------
// lane = (slot = lane>>4, c8 = lane&15); lane owns channels c8*8..c8*8+7 of its slot's edge.
__global__ void gat1_agg_kernel(const int* __restrict__ rowptr, const int* __restrict__ csr_src,
                                const ushort_t* __restrict__ h1b,
                                const ushort_t* __restrict__ alpha1,
                                const float* __restrict__ b1, ushort_t* __restrict__ hmidb, int n) {
  int lane = threadIdx.x & 63;
  int w = threadIdx.x >> 6;
  int dst = blockIdx.x * 4 + w;
  if (dst >= n) return;
  int beg = rowptr[dst], end = rowptr[dst + 1];
  int slot = lane >> 4, c8 = lane & 15;
  int hh = c8 >> 1;
  float acc[8] = {};
  #pragma unroll 2
  for (int e = beg + slot; e < end; e += 4) {
    int si = csr_src[e];
    float a = bf1(alpha1[(size_t)e * 8 + hh]);
    uint4 hv = *(const uint4*)(h1b + (size_t)si * 128 + c8 * 8);
    acc[0] = fmaf(a, bfl(hv.x), acc[0]);
    acc[1] = fmaf(a, bfh(hv.x), acc[1]);
    acc[2] = fmaf(a, bfl(hv.y), acc[2]);
    acc[3] = fmaf(a, bfh(hv.y), acc[3]);
    acc[4] = fmaf(a, bfl(hv.z), acc[4]);
    acc[5] = fmaf(a, bfh(hv.z), acc[5]);
    acc[6] = fmaf(a, bfl(hv.w), acc[6]);
    acc[7] = fmaf(a, bfh(hv.w), acc[7]);
  }
  #pragma unroll
  for (int i = 0; i < 8; ++i) {
    acc[i] += __shfl_xor(acc[i], 16);
    acc[i] += __shfl_xor(acc[i], 32);
  }
  if (slot == 0) {
    ushort_t ob[8];
    #pragma unroll
    for (int i = 0; i < 8; ++i) {
      float v = acc[i] + b1[c8 * 8 + i];
      v = v > 0.f ? v : (__expf(v) - 1.f);
      ob[i] = f2bf(v);
    }
    *(uint4*)(hmidb + (size_t)dst * 128 + c8 * 8) = *(uint4*)ob;
  }
}

// ---------------- GEMM2 + att2 fused: h2b(bf16) = hmid(bf16) @ W2; a_s2/a_d2 (f32) ----------------
__global__ void gemm2_att2_kernel(const ushort_t* __restrict__ hmidb, const float* __restrict__ W2,
                                  const float* __restrict__ asw, const float* __restrict__ adw,
                                  ushort_t* __restrict__ h2b, float* __restrict__ a_s2,
                                  float* __restrict__ a_d2, int n) {
  __shared__ float w[128 * 16];
  int t = threadIdx.x;
  for (int i = t; i < 128 * 16; i += 256) w[i] = W2[i];
  __syncthreads();
  int gid = blockIdx.x * 256 + t;
  int node = gid >> 4, c = gid & 15;
  if (node >= n) return;
  const ushort_t* row = &hmidb[(size_t)node * 128];
  float acc = 0.f;
  #pragma unroll 4
  for (int k = 0; k < 128; k += 2) {
    uint_t u = *(const uint_t*)(row + k);
    acc += bfl(u) * w[k * 16 + c] + bfh(u) * w[(k + 1) * 16 + c];
  }
  h2b[(size_t)node * 16 + c] = f2bf(acc);
  float ps = acc * asw[c], pd = acc * adw[c];
  #pragma unroll
  for (int m = 1; m < 16; m <<= 1) { ps += __shfl_xor(ps, m); pd += __shfl_xor(pd, m); }
  if (c == 0) { a_s2[node] = ps; a_d2[node] = pd; }
}

// ---------------- alpha2: normalized attention weights, layer 2 (1 head) ----------------
__global__ void alpha2_kernel(const int* __restrict__ rowptr, const int* __restrict__ csr_src,
                              const float* __restrict__ a_s2, const float* __restrict__ a_d2,
                              float* __restrict__ alpha2, int n) {
  int t = threadIdx.x & 63;
  int w = threadIdx.x >> 6;
  int dst = blockIdx.x * 4 + w;
  if (dst >= n) return;
  int beg = rowptr[dst], end = rowptr[dst + 1];
  if (beg == end) return;
  float adv = a_d2[dst];
  float M = -1e30f, S = 0.f;
  for (int base = beg; base < end; base += 64) {
    int eidx = base + t;
    bool valid = eidx < end;
    int s = csr_src[valid ? eidx : beg];
    float e = a_s2[s] + adv;
    e = e > 0.f ? e : 0.2f * e;
    e = valid ? e : -1e30f;
    float m = e;
    #pragma unroll
    for (int o = 1; o < 64; o <<= 1) m = fmaxf(m, __shfl_xor(m, o));
    float nm = fmaxf(M, m);
    float p = valid ? __expf(e - nm) : 0.f;
    float ps = p;
    #pragma unroll
    for (int o = 1; o < 64; o <<= 1) ps += __shfl_xor(ps, o);
    S = S * __expf(M - nm) + ps;
    M = nm;
  }
  float inv = 1.f / (S + 1e-16f);
  for (int base = beg; base < end; base += 64) {
    int eidx = base + t;
    if (eidx < end) {
      int s = csr_src[eidx];
      float e = a_s2[s] + adv;
      e = e > 0.f ? e : 0.2f * e;
      alpha2[eidx] = __expf(e - M) * inv;
    }
  }
}

// ---------------- GAT layer 2 aggregate + pooled atomics (16-lane group per dst) ----------------
__global__ void gat2_agg_kernel(const int* __restrict__ rowptr, const int* __restrict__ csr_src,
                                const ushort_t* __restrict__ h2b,
                                const float* __restrict__ alpha2, const float* __restrict__ b2,
                                const int* __restrict__ batch,
                                float* __restrict__ pooled, float* __restrict__ cntb,
                                int n, int G) {
  __shared__ float pooledL[17][16];
  __shared__ float cntL[17];
  int t = threadIdx.x;
  if (t < 17) cntL[t] = 0.f;
  for (int i = t; i < 17 * 16; i += 256) ((float*)pooledL)[i] = 0.f;
  __syncthreads();

  int grp = t >> 4, c = t & 15;
  int dst = blockIdx.x * 16 + grp;
  int gfirst = batch[blockIdx.x * 16];

  if (dst < n) {
    int beg = rowptr[dst], end = rowptr[dst + 1];
    float acc = 0.f;
    for (int base = beg; base < end; base += 16) {
      int cnt = min(16, end - base);
      int idx = min(base + c, end - 1);
      int sv = csr_src[idx];
      float av = alpha2[idx];
      #pragma unroll 4
      for (int i = 0; i < cnt; ++i) {
        float ai = __shfl(av, i, 16);
        int   si = __shfl(sv, i, 16);
        acc = fmaf(ai, bf1(h2b[(size_t)si * 16 + c]), acc);
      }
    }
    float v = acc + b2[c];
    int g = batch[dst];
    int gi = g - gfirst;
    if (gi <= 16) {
      atomicAdd(&pooledL[gi][c], v);
      if (c == 0) atomicAdd(&cntL[gi], 1.f);
    } else {
      atomicAdd(&pooled[g * 16 + c], v);
      if (c == 0) atomicAdd(&cntb[g], 1.f);
    }
  }
  __syncthreads();

  int w = t >> 5, lane32 = t & 31;
  for (int gi = w; gi < 17; gi += 8) {
    if (cntL[gi] > 0.f) {
      int g = gfirst + gi;
      if (lane32 < 16) atomicAdd(&pooled[g * 16 + lane32], pooledL[gi][lane32]);
      else if (lane32 == 16) atomicAdd(&cntb[g], cntL[gi]);
    }
  }
}

// ---------------- final: mean + log_softmax ----------------
__global__ void final_kernel(const float* __restrict__ pooled, const float* __restrict__ cntb,
                             float* __restrict__ out, int G) {
  int g = threadIdx.x;
  if (g >= G) return;
  float c = fmaxf(cntb[g], 1.f);
  float v[16];
  float m = -1e30f;
  #pragma unroll
  for (int i = 0; i < 16; ++i) { v[i] = pooled[g * 16 + i] / c; m = fmaxf(m, v[i]); }
  float s = 0.f;
  #pragma unroll
  for (int i = 0; i < 16; ++i) s += __expf(v[i] - m);
  float ls = logf(s);
  #pragma unroll
  for (int i = 0; i < 16; ++i) out[g * 16 + i] = v[i] - m - ls;
}

// ---------------- launcher ----------------
extern "C" void kernel_launch(void* const* d_in, const int* in_sizes, int n_in,
                              void* d_out, int out_size, void* d_ws, size_t ws_size,
                              hipStream_t stream) {
  const float* x    = (const float*)d_in[0];
  const int*   eidx = (const int*)  d_in[1];
  const int*   batch= (const int*)  d_in[2];
  const float* W1   = (const float*)d_in[3];
  const float* as1w = (const float*)d_in[4];
  const float* ad1w = (const float*)d_in[5];
  const float* b1   = (const float*)d_in[6];
  const float* W2   = (const float*)d_in[7];
  const float* as2w = (const float*)d_in[8];
  const float* ad2w = (const float*)d_in[9];
  const float* b2   = (const float*)d_in[10];
  float* out = (float*)d_out;

  int N = in_sizes[0] / 128;
  int E = in_sizes[1] / 2;
  int G = out_size / 16;
  const int* esrc = eidx;
  const int* edst = eidx + E;

  int NB = (N + 127) >> 7;
  int nblkA = (E + EPB - 1) / EPB;

  char* p = (char*)d_ws;
  auto alloc = [&](size_t bytes) {
    char* r = p;
    p += (bytes + 255) & ~(size_t)255;
    return r;
  };
  ushort_t* h1b = (ushort_t*)alloc((size_t)N * 128 * 2);
  ushort_t* hmidb = (ushort_t*)alloc((size_t)N * 128 * 2);
  ushort_t* h2b = (ushort_t*)alloc((size_t)N * 16 * 2);
  float* as1  = (float*)alloc((size_t)N * 8 * 4);
  float* ad1  = (float*)alloc((size_t)N * 8 * 4);
  float* as2  = (float*)alloc((size_t)N * 4);
  float* ad2  = (float*)alloc((size_t)N * 4);
  // union: pairs (E*4 B) is dead before alpha1/alpha2 are produced
  size_t a1sz = (size_t)E * 8 * 2, a2sz = (size_t)E * 4;
  size_t unionSz = a1sz + a2sz;
  char* U = alloc(unionSz);
  uint_t* pairs = (uint_t*)U;
  ushort_t* alpha1 = (ushort_t*)U;
  float* alpha2 = (float*)(U + a1sz);
  float* pooled = (float*)alloc((size_t)(G * 16 + G) * 4);
  float* cntb = pooled + G * 16;
  int* rowptr = (int*)alloc((size_t)(N + 1) * 4);
  int* csr    = (int*)alloc((size_t)E * 4);
  int* gcount = (int*)alloc((size_t)(NBMAX + 1) * 4);
  int* boff   = (int*)alloc((size_t)(NBMAX + 1) * 4);
  int* myBase = (int*)alloc((size_t)nblkA * NB * 4);

  hipMemsetAsync(gcount, 0, (size_t)(NBMAX + 1) * 4, stream);
  hipMemsetAsync(pooled, 0, (size_t)(G * 16 + G) * 4, stream);

  bucket_hist_kernel<<<nblkA, 256, 0, stream>>>(edst, gcount, myBase, E, NB);
  bucket_scan_kernel<<<1, 1024, 0, stream>>>(gcount, boff, NB);
  bucket_scatter_kernel<<<nblkA, 256, 0, stream>>>(esrc, edst, boff, myBase, pairs, E, NB);
  bucket_csr_kernel<<<NB, 128, 0, stream>>>(pairs, boff, rowptr, csr, N, NB);

  gemm1_att1_kernel<<<(N + 63) / 64, 256, 0, stream>>>(x, W1, as1w, ad1w, h1b, as1, ad1, N);
  alpha1_kernel<<<(N + 3) / 4, 256, 0, stream>>>(rowptr, csr, as1, ad1, alpha1, N);
  gat1_agg_kernel<<<(N + 3) / 4, 256, 0, stream>>>(rowptr, csr, h1b, alpha1, b1, hmidb, N);
  gemm2_att2_kernel<<<(N * 16 + 255) / 256, 256, 0, stream>>>(hmidb, W2, as2w, ad2w, h2b, as2, ad2, N);
  alpha2_kernel<<<(N + 3) / 4, 256, 0, stream>>>(rowptr, csr, as2, ad2, alpha2, N);
  gat2_agg_kernel<<<(N + 15) / 16, 256, 0, stream>>>(rowptr, csr, h2b, alpha2, b2, batch, pooled, cntb, N, G);
  final_kernel<<<1, (G + 63) / 64 * 64, 0, stream>>>(pooled, cntb, out, G);
}

// Round 8
// 426.001 us; speedup vs baseline: 1.4848x; 1.1304x over previous
//
#include <hip/hip_runtime.h>
#include <cstdint>
#include <cstddef>

typedef unsigned short ushort_t;
typedef unsigned int uint_t;
typedef __attribute__((ext_vector_type(8))) short bf16x8;
typedef __attribute__((ext_vector_type(4))) float f32x4;

#define NBMAX 1024   // max buckets (N <= 131072)
#define EPB   16384  // edges per block in hist/scatter passes
#define LDK   136    // padded k-stride (bf16 units) for LDS W^T

__device__ inline ushort_t f2bf(float f) {
  uint_t u = __float_as_uint(f);
  uint_t r = (u + 0x7fffu + ((u >> 16) & 1u)) >> 16;
  return (ushort_t)r;
}
__device__ inline float bfl(uint_t u) { return __uint_as_float(u << 16); }
__device__ inline float bfh(uint_t u) { return __uint_as_float(u & 0xffff0000u); }
__device__ inline float bf1(ushort_t v) { return __uint_as_float(((uint_t)v) << 16); }

// ---------------- CSR construction: bucketed counting sort ----------------

__global__ void bucket_hist_kernel(const int* __restrict__ edst, int* __restrict__ gcount,
                                   int* __restrict__ myBase, int E, int NB) {
  __shared__ int hist[NBMAX];
  int t = threadIdx.x;
  int blk = blockIdx.x;
  for (int i = t; i < NB; i += 256) hist[i] = 0;
  __syncthreads();
  int b0 = blk * EPB, e1 = min(b0 + EPB, E);
  for (int i = b0 + t; i < e1; i += 256) atomicAdd(&hist[edst[i] >> 7], 1);
  __syncthreads();
  for (int i = t; i < NB; i += 256) {
    int c = hist[i];
    myBase[(size_t)blk * NB + i] = c ? atomicAdd(&gcount[i], c) : 0;
  }
}

__global__ void bucket_scan_kernel(const int* __restrict__ gcount, int* __restrict__ boff, int NB) {
  __shared__ int ws[16];
  int t = threadIdx.x;
  int lane = t & 63, w = t >> 6;
  int v = (t < NB) ? gcount[t] : 0;
  for (int o = 1; o < 64; o <<= 1) { int y = __shfl_up(v, o); if (lane >= o) v += y; }
  if (lane == 63) ws[w] = v;
  __syncthreads();
  if (t < 16) {
    int s = ws[t];
    for (int o = 1; o < 16; o <<= 1) { int y = __shfl_up(s, o); if (t >= o) s += y; }
    ws[t] = s;
  }
  __syncthreads();
  if (w > 0) v += ws[w - 1];
  if (t < NB) boff[t + 1] = v;
  if (t == 0) boff[0] = 0;
}

// packed pair: (dst & 127) << 25 | src   (requires src < 2^25)
__global__ void bucket_scatter_kernel(const int* __restrict__ esrc, const int* __restrict__ edst,
                                      const int* __restrict__ boff, const int* __restrict__ myBase,
                                      uint_t* __restrict__ pairs, int E, int NB) {
  __shared__ int cursor[NBMAX];
  int t = threadIdx.x;
  int blk = blockIdx.x;
  for (int i = t; i < NB; i += 256) cursor[i] = boff[i] + myBase[(size_t)blk * NB + i];
  __syncthreads();
  int b0 = blk * EPB, e1 = min(b0 + EPB, E);
  for (int i = b0 + t; i < e1; i += 256) {
    int d = edst[i], s = esrc[i];
    int pos = atomicAdd(&cursor[d >> 7], 1);
    pairs[pos] = ((uint_t)(d & 127) << 25) | (uint_t)s;
  }
}

__global__ void bucket_csr_kernel(const uint_t* __restrict__ pairs, const int* __restrict__ boff,
                                  int* __restrict__ rowptr, int* __restrict__ csr, int n, int NB) {
  __shared__ int cnt[128];
  __shared__ int ws2[2];
  int b = blockIdx.x;
  int t = threadIdx.x;   // 128 threads
  int lo = boff[b], hi = boff[b + 1];
  int D0 = b << 7;
  cnt[t] = 0;
  __syncthreads();
  for (int i = lo + t; i < hi; i += 128) atomicAdd(&cnt[pairs[i] >> 25], 1);
  __syncthreads();
  int lane = t & 63, w = t >> 6;
  int v = cnt[t];
  int vx = v;
  for (int o = 1; o < 64; o <<= 1) { int y = __shfl_up(vx, o); if (lane >= o) vx += y; }
  if (lane == 63) ws2[w] = vx;
  __syncthreads();
  int incl = vx + (w ? ws2[0] : 0);
  int excl = incl - v;
  int d = D0 + t;
  if (d <= n) rowptr[d] = lo + excl;
  __syncthreads();
  cnt[t] = excl;
  __syncthreads();
  for (int i = lo + t; i < hi; i += 128) {
    uint_t pr = pairs[i];
    int pos = atomicAdd(&cnt[pr >> 25], 1);
    csr[lo + pos] = (int)(pr & 0x1FFFFFFu);
  }
}

// ---------------- GEMM1 + att1 fused (MFMA): h1b(bf16) = x@W1; a_s/a_d (f32) ----------------
// Block 256 = 4 waves; wave computes 16 rows x 128 cols. W1^T staged bf16 in LDS.
// Slot bijection: k = c*32 + (lane>>4)*8 + j  (same for A and B => contraction correct).
// D layout (HW-verified m89): col = lane&15, row = (lane>>4)*4 + reg.
__global__ void gemm1_att1_kernel(const float* __restrict__ x, const float* __restrict__ W,
                                  const float* __restrict__ asw, const float* __restrict__ adw,
                                  ushort_t* __restrict__ h1b, float* __restrict__ a_s,
                                  float* __restrict__ a_d, int n) {
  __shared__ ushort_t wT[128 * LDK];
  int t = threadIdx.x;
  {
    int nn = t & 127;
    int kp0 = t >> 7;                    // 0..1
    for (int kp = kp0; kp < 64; kp += 2) {
      float w0 = W[(size_t)(2 * kp) * 128 + nn];
      float w1 = W[(size_t)(2 * kp + 1) * 128 + nn];
      *(uint_t*)&wT[nn * LDK + 2 * kp] = (uint_t)f2bf(w0) | ((uint_t)f2bf(w1) << 16);
    }
  }
  __syncthreads();

  int lane = t & 63, w = t >> 6;
  int g = lane >> 4, cl = lane & 15;
  int rowA = blockIdx.x * 64 + w * 16 + cl;       // A-operand row for this lane
  const float* xr = x + (size_t)(rowA < n ? rowA : 0) * 128;

  bf16x8 afr[4];
  #pragma unroll
  for (int c = 0; c < 4; ++c) {
    float4 v0 = *(const float4*)(xr + c * 32 + g * 8);
    float4 v1 = *(const float4*)(xr + c * 32 + g * 8 + 4);
    bf16x8 a;
    a[0] = (short)f2bf(v0.x); a[1] = (short)f2bf(v0.y);
    a[2] = (short)f2bf(v0.z); a[3] = (short)f2bf(v0.w);
    a[4] = (short)f2bf(v1.x); a[5] = (short)f2bf(v1.y);
    a[6] = (short)f2bf(v1.z); a[7] = (short)f2bf(v1.w);
    afr[c] = a;
  }

  int orow0 = blockIdx.x * 64 + w * 16 + g * 4;   // D rows base for this lane
  #pragma unroll 2
  for (int tt = 0; tt < 8; ++tt) {
    f32x4 acc = {0.f, 0.f, 0.f, 0.f};
    #pragma unroll
    for (int c = 0; c < 4; ++c) {
      bf16x8 bfr = *(const bf16x8*)&wT[(tt * 16 + cl) * LDK + c * 32 + g * 8];
      acc = __builtin_amdgcn_mfma_f32_16x16x32_bf16(afr[c], bfr, acc, 0, 0, 0);
    }
    float asv = asw[tt * 16 + cl], adv = adw[tt * 16 + cl];
    float ps[4], pd[4];
    ushort_t hb[4];
    #pragma unroll
    for (int r = 0; r < 4; ++r) {
      float v = acc[r];
      hb[r] = f2bf(v);
      ps[r] = v * asv; pd[r] = v * adv;
    }
    #pragma unroll
    for (int o = 1; o < 16; o <<= 1) {
      #pragma unroll
      for (int r = 0; r < 4; ++r) { ps[r] += __shfl_xor(ps[r], o); pd[r] += __shfl_xor(pd[r], o); }
    }
    #pragma unroll
    for (int r = 0; r < 4; ++r) {
      int rr = orow0 + r;
      if (rr < n) {
        h1b[(size_t)rr * 128 + tt * 16 + cl] = hb[r];
        if (cl == 0) {
          a_s[(size_t)rr * 8 + tt] = ps[r];
          a_d[(size_t)rr * 8 + tt] = pd[r];
        }
      }
    }
  }
}

// ---------------- alpha1: normalized attention weights, layer 1 ----------------
__global__ void alpha1_kernel(const int* __restrict__ rowptr, const int* __restrict__ csr_src,
                              const float* __restrict__ a_s, const float* __restrict__ a_d,
                              ushort_t* __restrict__ alpha1, int n) {
  int t = threadIdx.x & 63;
  int w = threadIdx.x >> 6;
  int dst = blockIdx.x * 4 + w;
  if (dst >= n) return;
  int beg = rowptr[dst], end = rowptr[dst + 1];
  if (beg == end) return;
  int h = t & 7, el = t >> 3;
  float adv = a_d[(size_t)dst * 8 + h];
  float M = -1e30f, S = 0.f;
  for (int base = beg; base < end; base += 8) {
    int eidx = base + el;
    bool valid = eidx < end;
    int s = csr_src[valid ? eidx : beg];
    float e = a_s[(size_t)s * 8 + h] + adv;
    e = e > 0.f ? e : 0.2f * e;
    e = valid ? e : -1e30f;
    float m = e;
    m = fmaxf(m, __shfl_xor(m, 8));
    m = fmaxf(m, __shfl_xor(m, 16));
    m = fmaxf(m, __shfl_xor(m, 32));
    float nm = fmaxf(M, m);
    float p = valid ? __expf(e - nm) : 0.f;
    float ps = p;
    ps += __shfl_xor(ps, 8);
    ps += __shfl_xor(ps, 16);
    ps += __shfl_xor(ps, 32);
    S = S * __expf(M - nm) + ps;
    M = nm;
  }
  float inv = 1.f / (S + 1e-16f);
  for (int base = beg; base < end; base += 8) {
    int eidx = base + el;
    if (eidx < end) {
      int s = csr_src[eidx];
      float e = a_s[(size_t)s * 8 + h] + adv;
      e = e > 0.f ? e : 0.2f * e;
      alpha1[(size_t)eidx * 8 + h] = f2bf(__expf(e - M) * inv);
    }
  }
}

// ---------------- GAT layer 1 aggregate: 4 edges/wave, 16 lanes/edge ----------------
__global__ void gat1_agg_kernel(const int* __restrict__ rowptr, const int* __restrict__ csr_src,
                                const ushort_t* __restrict__ h1b,
                                const ushort_t* __restrict__ alpha1,
                                const float* __restrict__ b1, ushort_t* __restrict__ hmidb, int n) {
  int lane = threadIdx.x & 63;
  int w = threadIdx.x >> 6;
  int dst = blockIdx.x * 4 + w;
  if (dst >= n) return;
  int beg = rowptr[dst], end = rowptr[dst + 1];
  int slot = lane >> 4, c8 = lane & 15;
  int hh = c8 >> 1;
  float acc[8] = {};
  #pragma unroll 2
  for (int e = beg + slot; e < end; e += 4) {
    int si = csr_src[e];
    float a = bf1(alpha1[(size_t)e * 8 + hh]);
    uint4 hv = *(const uint4*)(h1b + (size_t)si * 128 + c8 * 8);
    acc[0] = fmaf(a, bfl(hv.x), acc[0]);
    acc[1] = fmaf(a, bfh(hv.x), acc[1]);
    acc[2] = fmaf(a, bfl(hv.y), acc[2]);
    acc[3] = fmaf(a, bfh(hv.y), acc[3]);
    acc[4] = fmaf(a, bfl(hv.z), acc[4]);
    acc[5] = fmaf(a, bfh(hv.z), acc[5]);
    acc[6] = fmaf(a, bfl(hv.w), acc[6]);
    acc[7] = fmaf(a, bfh(hv.w), acc[7]);
  }
  #pragma unroll
  for (int i = 0; i < 8; ++i) {
    acc[i] += __shfl_xor(acc[i], 16);
    acc[i] += __shfl_xor(acc[i], 32);
  }
  if (slot == 0) {
    ushort_t ob[8];
    #pragma unroll
    for (int i = 0; i < 8; ++i) {
      float v = acc[i] + b1[c8 * 8 + i];
      v = v > 0.f ? v : (__expf(v) - 1.f);
      ob[i] = f2bf(v);
    }
    *(uint4*)(hmidb + (size_t)dst * 128 + c8 * 8) = *(uint4*)ob;
  }
}

// ---------------- GEMM2 + att2 fused (MFMA): h2b = hmid(bf16) @ W2; a_s2/a_d2 ----------------
__global__ void gemm2_att2_kernel(const ushort_t* __restrict__ hmidb, const float* __restrict__ W2,
                                  const float* __restrict__ asw, const float* __restrict__ adw,
                                  ushort_t* __restrict__ h2b, float* __restrict__ a_s2,
                                  float* __restrict__ a_d2, int n) {
  __shared__ ushort_t wT[16 * LDK];
  int t = threadIdx.x;
  if (t < 128) {
    int nn = t & 15, kp0 = t >> 4;     // 0..7
    for (int kp = kp0; kp < 64; kp += 8) {
      float w0 = W2[(size_t)(2 * kp) * 16 + nn];
      float w1 = W2[(size_t)(2 * kp + 1) * 16 + nn];
      *(uint_t*)&wT[nn * LDK + 2 * kp] = (uint_t)f2bf(w0) | ((uint_t)f2bf(w1) << 16);
    }
  }
  __syncthreads();

  int lane = t & 63, w = t >> 6;
  int g = lane >> 4, cl = lane & 15;
  int rowA = blockIdx.x * 64 + w * 16 + cl;
  const ushort_t* hr = hmidb + (size_t)(rowA < n ? rowA : 0) * 128;

  f32x4 acc = {0.f, 0.f, 0.f, 0.f};
  #pragma unroll
  for (int c = 0; c < 4; ++c) {
    bf16x8 afr = *(const bf16x8*)(hr + c * 32 + g * 8);
    bf16x8 bfr = *(const bf16x8*)&wT[cl * LDK + c * 32 + g * 8];
    acc = __builtin_amdgcn_mfma_f32_16x16x32_bf16(afr, bfr, acc, 0, 0, 0);
  }
  float asv = asw[cl], adv = adw[cl];
  float ps[4], pd[4];
  ushort_t hb[4];
  #pragma unroll
  for (int r = 0; r < 4; ++r) {
    float v = acc[r];
    hb[r] = f2bf(v);
    ps[r] = v * asv; pd[r] = v * adv;
  }
  #pragma unroll
  for (int o = 1; o < 16; o <<= 1) {
    #pragma unroll
    for (int r = 0; r < 4; ++r) { ps[r] += __shfl_xor(ps[r], o); pd[r] += __shfl_xor(pd[r], o); }
  }
  int orow0 = blockIdx.x * 64 + w * 16 + g * 4;
  #pragma unroll
  for (int r = 0; r < 4; ++r) {
    int rr = orow0 + r;
    if (rr < n) {
      h2b[(size_t)rr * 16 + cl] = hb[r];
      if (cl == 0) { a_s2[rr] = ps[r]; a_d2[rr] = pd[r]; }
    }
  }
}

// ---------------- alpha2: normalized attention weights, layer 2 (1 head) ----------------
__global__ void alpha2_kernel(const int* __restrict__ rowptr, const int* __restrict__ csr_src,
                              const float* __restrict__ a_s2, const float* __restrict__ a_d2,
                              float* __restrict__ alpha2, int n) {
  int t = threadIdx.x & 63;
  int w = threadIdx.x >> 6;
  int dst = blockIdx.x * 4 + w;
  if (dst >= n) return;
  int beg = rowptr[dst], end = rowptr[dst + 1];
  if (beg == end) return;
  float adv = a_d2[dst];
  float M = -1e30f, S = 0.f;
  for (int base = beg; base < end; base += 64) {
    int eidx = base + t;
    bool valid = eidx < end;
    int s = csr_src[valid ? eidx : beg];
    float e = a_s2[s] + adv;
    e = e > 0.f ? e : 0.2f * e;
    e = valid ? e : -1e30f;
    float m = e;
    #pragma unroll
    for (int o = 1; o < 64; o <<= 1) m = fmaxf(m, __shfl_xor(m, o));
    float nm = fmaxf(M, m);
    float p = valid ? __expf(e - nm) : 0.f;
    float ps = p;
    #pragma unroll
    for (int o = 1; o < 64; o <<= 1) ps += __shfl_xor(ps, o);
    S = S * __expf(M - nm) + ps;
    M = nm;
  }
  float inv = 1.f / (S + 1e-16f);
  for (int base = beg; base < end; base += 64) {
    int eidx = base + t;
    if (eidx < end) {
      int s = csr_src[eidx];
      float e = a_s2[s] + adv;
      e = e > 0.f ? e : 0.2f * e;
      alpha2[eidx] = __expf(e - M) * inv;
    }
  }
}

// ---------------- GAT layer 2 aggregate + pooled atomics (16-lane group per dst) ----------------
__global__ void gat2_agg_kernel(const int* __restrict__ rowptr, const int* __restrict__ csr_src,
                                const ushort_t* __restrict__ h2b,
                                const float* __restrict__ alpha2, const float* __restrict__ b2,
                                const int* __restrict__ batch,
                                float* __restrict__ pooled, float* __restrict__ cntb,
                                int n, int G) {
  __shared__ float pooledL[17][16];
  __shared__ float cntL[17];
  int t = threadIdx.x;
  if (t < 17) cntL[t] = 0.f;
  for (int i = t; i < 17 * 16; i += 256) ((float*)pooledL)[i] = 0.f;
  __syncthreads();

  int grp = t >> 4, c = t & 15;
  int dst = blockIdx.x * 16 + grp;
  int gfirst = batch[blockIdx.x * 16];

  if (dst < n) {
    int beg = rowptr[dst], end = rowptr[dst + 1];
    float acc = 0.f;
    for (int base = beg; base < end; base += 16) {
      int cnt = min(16, end - base);
      int idx = min(base + c, end - 1);
      int sv = csr_src[idx];
      float av = alpha2[idx];
      #pragma unroll 4
      for (int i = 0; i < cnt; ++i) {
        float ai = __shfl(av, i, 16);
        int   si = __shfl(sv, i, 16);
        acc = fmaf(ai, bf1(h2b[(size_t)si * 16 + c]), acc);
      }
    }
    float v = acc + b2[c];
    int g = batch[dst];
    int gi = g - gfirst;
    if (gi <= 16) {
      atomicAdd(&pooledL[gi][c], v);
      if (c == 0) atomicAdd(&cntL[gi], 1.f);
    } else {
      atomicAdd(&pooled[g * 16 + c], v);
      if (c == 0) atomicAdd(&cntb[g], 1.f);
    }
  }
  __syncthreads();

  int w = t >> 5, lane32 = t & 31;
  for (int gi = w; gi < 17; gi += 8) {
    if (cntL[gi] > 0.f) {
      int g = gfirst + gi;
      if (lane32 < 16) atomicAdd(&pooled[g * 16 + lane32], pooledL[gi][lane32]);
      else if (lane32 == 16) atomicAdd(&cntb[g], cntL[gi]);
    }
  }
}

// ---------------- final: mean + log_softmax ----------------
__global__ void final_kernel(const float* __restrict__ pooled, const float* __restrict__ cntb,
                             float* __restrict__ out, int G) {
  int g = threadIdx.x;
  if (g >= G) return;
  float c = fmaxf(cntb[g], 1.f);
  float v[16];
  float m = -1e30f;
  #pragma unroll
  for (int i = 0; i < 16; ++i) { v[i] = pooled[g * 16 + i] / c; m = fmaxf(m, v[i]); }
  float s = 0.f;
  #pragma unroll
  for (int i = 0; i < 16; ++i) s += __expf(v[i] - m);
  float ls = logf(s);
  #pragma unroll
  for (int i = 0; i < 16; ++i) out[g * 16 + i] = v[i] - m - ls;
}

// ---------------- launcher ----------------
extern "C" void kernel_launch(void* const* d_in, const int* in_sizes, int n_in,
                              void* d_out, int out_size, void* d_ws, size_t ws_size,
                              hipStream_t stream) {
  const float* x    = (const float*)d_in[0];
  const int*   eidx = (const int*)  d_in[1];
  const int*   batch= (const int*)  d_in[2];
  const float* W1   = (const float*)d_in[3];
  const float* as1w = (const float*)d_in[4];
  const float* ad1w = (const float*)d_in[5];
  const float* b1   = (const float*)d_in[6];
  const float* W2   = (const float*)d_in[7];
  const float* as2w = (const float*)d_in[8];
  const float* ad2w = (const float*)d_in[9];
  const float* b2   = (const float*)d_in[10];
  float* out = (float*)d_out;

  int N = in_sizes[0] / 128;
  int E = in_sizes[1] / 2;
  int G = out_size / 16;
  const int* esrc = eidx;
  const int* edst = eidx + E;

  int NB = (N + 127) >> 7;
  int nblkA = (E + EPB - 1) / EPB;

  char* p = (char*)d_ws;
  auto alloc = [&](size_t bytes) {
    char* r = p;
    p += (bytes + 255) & ~(size_t)255;
    return r;
  };
  ushort_t* h1b = (ushort_t*)alloc((size_t)N * 128 * 2);
  ushort_t* hmidb = (ushort_t*)alloc((size_t)N * 128 * 2);
  ushort_t* h2b = (ushort_t*)alloc((size_t)N * 16 * 2);
  float* as1  = (float*)alloc((size_t)N * 8 * 4);
  float* ad1  = (float*)alloc((size_t)N * 8 * 4);
  float* as2  = (float*)alloc((size_t)N * 4);
  float* ad2  = (float*)alloc((size_t)N * 4);
  // union: pairs (E*4 B) is dead before alpha1/alpha2 are produced
  size_t a1sz = (size_t)E * 8 * 2, a2sz = (size_t)E * 4;
  size_t unionSz = a1sz + a2sz;
  char* U = alloc(unionSz);
  uint_t* pairs = (uint_t*)U;
  ushort_t* alpha1 = (ushort_t*)U;
  float* alpha2 = (float*)(U + a1sz);
  float* pooled = (float*)alloc((size_t)(G * 16 + G) * 4);
  float* cntb = pooled + G * 16;
  int* rowptr = (int*)alloc((size_t)(N + 1) * 4);
  int* csr    = (int*)alloc((size_t)E * 4);
  int* gcount = (int*)alloc((size_t)(NBMAX + 1) * 4);
  int* boff   = (int*)alloc((size_t)(NBMAX + 1) * 4);
  int* myBase = (int*)alloc((size_t)nblkA * NB * 4);

  hipMemsetAsync(gcount, 0, (size_t)(NBMAX + 1) * 4, stream);
  hipMemsetAsync(pooled, 0, (size_t)(G * 16 + G) * 4, stream);

  bucket_hist_kernel<<<nblkA, 256, 0, stream>>>(edst, gcount, myBase, E, NB);
  bucket_scan_kernel<<<1, 1024, 0, stream>>>(gcount, boff, NB);
  bucket_scatter_kernel<<<nblkA, 256, 0, stream>>>(esrc, edst, boff, myBase, pairs, E, NB);
  bucket_csr_kernel<<<NB, 128, 0, stream>>>(pairs, boff, rowptr, csr, N, NB);

  gemm1_att1_kernel<<<(N + 63) / 64, 256, 0, stream>>>(x, W1, as1w, ad1w, h1b, as1, ad1, N);
  alpha1_kernel<<<(N + 3) / 4, 256, 0, stream>>>(rowptr, csr, as1, ad1, alpha1, N);
  gat1_agg_kernel<<<(N + 3) / 4, 256, 0, stream>>>(rowptr, csr, h1b, alpha1, b1, hmidb, N);
  gemm2_att2_kernel<<<(N + 63) / 64, 256, 0, stream>>>(hmidb, W2, as2w, ad2w, h2b, as2, ad2, N);
  alpha2_kernel<<<(N + 3) / 4, 256, 0, stream>>>(rowptr, csr, as2, ad2, alpha2, N);
  gat2_agg_kernel<<<(N + 15) / 16, 256, 0, stream>>>(rowptr, csr, h2b, alpha2, b2, batch, pooled, cntb, N, G);
  final_kernel<<<1, (G + 63) / 64 * 64, 0, stream>>>(pooled, cntb, out, G);
}